// Round 2
// baseline (878.444 us; speedup 1.0000x reference)
//
#include <hip/hip_runtime.h>
#include <hip/hip_bf16.h>

#define BLOCK 256

// out[b,i,j,h] = W[h, rel_pos[b,i,j]]  — float32 gather of 12-float records.
// Record = 48 B = 3 x 16B chunks; one thread per 16B chunk q:
//   p = q/3 (record), s = q%3 (covers floats [4s, 4s+4) of the record).
// Table lives in LDS as [class][head] (stride 12 floats); source address
// 48c + 16s bytes is 16B-aligned -> single ds_read_b128 per chunk.
__global__ __launch_bounds__(BLOCK) void gather12_kernel(
    const int* __restrict__ rel_pos,
    const float* __restrict__ W,        // [12][64] float32
    float4* __restrict__ out,
    unsigned int total_chunks)
{
    __shared__ float tab[64 * 12];      // tab[c*12 + h] = W[h][c]

    const int t = threadIdx.x;
    for (int i = t; i < 768; i += BLOCK) {
        int h = i >> 6;                 // 0..11
        int c = i & 63;                 // 0..63
        tab[c * 12 + h] = W[i];         // W is [12][64] row-major: W[h*64+c]
    }
    __syncthreads();

    const unsigned int stride = gridDim.x * BLOCK;
    for (unsigned int q = blockIdx.x * BLOCK + t; q < total_chunks; q += stride) {
        unsigned int p = q / 3u;        // record index (magic-mul div)
        unsigned int s = q - p * 3u;    // 0,1,2
        unsigned int c = (unsigned int)rel_pos[p];   // class 0..63
        const float4 v = *(const float4*)(tab + c * 12u + 4u * s);
        out[q] = v;                     // coalesced global_store_dwordx4
    }
}

extern "C" void kernel_launch(void* const* d_in, const int* in_sizes, int n_in,
                              void* d_out, int out_size, void* d_ws, size_t ws_size,
                              hipStream_t stream)
{
    const int* rel_pos = (const int*)d_in[0];
    // d_in[1] = hidden_states: unused (reference only uses its dtype)
    const float* W = (const float*)d_in[2];

    const long long n_rec = in_sizes[0];                       // 4*2048*2048
    const unsigned int total_chunks = (unsigned int)(n_rec * 3ll); // 48B/rec / 16B

    const int iters = 8;
    long long threads_needed = ((long long)total_chunks + iters - 1) / iters;
    int blocks = (int)((threads_needed + BLOCK - 1) / BLOCK);
    if (blocks < 1) blocks = 1;

    gather12_kernel<<<blocks, BLOCK, 0, stream>>>(rel_pos, W, (float4*)d_out, total_chunks);
}

// Round 4
// 830.353 us; speedup vs baseline: 1.0579x; 1.0579x over previous
//
#include <hip/hip_runtime.h>
#include <hip/hip_bf16.h>

#define BLOCK 256

typedef float f4 __attribute__((ext_vector_type(4)));  // native vec for nontemporal builtin

// out[b,i,j,h] = W[h, rel_pos[b,i,j]] — float32 gather, 12 floats/record.
// Record = 48 B = 3 x float4 chunks. Each block owns 256 records = 768 chunks.
// Phase 1: coalesced index load -> LDS cls[256]; table W^T -> LDS tab[64][12].
// Phase 2: thread t produces chunks {t, t+256, t+512} of the tile —
// compile-time unrolled, 3 independent LDS gathers then 3 independent
// coalesced nontemporal dwordx4 stores (explicit MLP; no runtime div).
__global__ __launch_bounds__(BLOCK) void gather12_v3(
    const int* __restrict__ rel_pos,
    const float* __restrict__ W,        // [12][64] float32
    f4* __restrict__ out,
    unsigned int n_rec)
{
    __shared__ float tab[64 * 12];      // tab[c*12+h] = W[h][c]; chunk src 16B-aligned
    __shared__ int cls[BLOCK];

    const int t = threadIdx.x;
    for (int i = t; i < 768; i += BLOCK) {
        int h = i >> 6;                 // 0..11
        int c = i & 63;                 // 0..63
        tab[c * 12 + h] = W[i];
    }

    const unsigned int recBase = blockIdx.x * BLOCK;
    const unsigned int r = recBase + t;
    cls[t] = (r < n_rec) ? rel_pos[r] : 0;   // one coalesced dword/lane
    __syncthreads();

    const unsigned long long chunkBase = (unsigned long long)recBase * 3ull;
    const unsigned long long total_chunks = (unsigned long long)n_rec * 3ull;

    f4 v[3];
#pragma unroll
    for (int k = 0; k < 3; ++k) {
        unsigned int j = (unsigned int)t + BLOCK * k;   // 0..767 within tile
        unsigned int p = j / 3u;                        // const divisor -> magic mul
        unsigned int s = j - p * 3u;                    // 0,1,2
        unsigned int c = (unsigned int)cls[p];          // LDS, 3-way broadcast (free)
        v[k] = *(const f4*)(tab + c * 12u + 4u * s);    // ds_read_b128
    }
#pragma unroll
    for (int k = 0; k < 3; ++k) {
        unsigned int j = (unsigned int)t + BLOCK * k;
        if (chunkBase + j < total_chunks)
            __builtin_nontemporal_store(v[k], &out[chunkBase + j]);
    }
}

extern "C" void kernel_launch(void* const* d_in, const int* in_sizes, int n_in,
                              void* d_out, int out_size, void* d_ws, size_t ws_size,
                              hipStream_t stream)
{
    const int* rel_pos = (const int*)d_in[0];
    // d_in[1] = hidden_states: unused (reference only uses its dtype)
    const float* W = (const float*)d_in[2];

    const unsigned int n_rec = (unsigned int)in_sizes[0];   // 4*2048*2048
    const int blocks = (int)((n_rec + BLOCK - 1) / BLOCK);  // 65536

    gather12_v3<<<blocks, BLOCK, 0, stream>>>(rel_pos, W, (f4*)d_out, n_rec);
}